// Round 17
// baseline (221.025 us; speedup 1.0000x reference)
//
#include <hip/hip_runtime.h>
#include <hip/hip_bf16.h>
#include <stdint.h>

// ---------------------------------------------------------------------------
// HilbertAttention pipeline, bf16 MFMA implementation.
//   x   = ([q|k|v] @ W1t^T)/3        (GEMM1 fused f32->bf16 A-staging, 256^2)
//   qkv = x @ Wqkvt^T                (GEMM2: 128^2, 2 WGs/CU)
//   attention (Hilbert, 128-seg, dil 2 -> 4096 groups of 64x64)
//   out = att @ Woutt^T  (f32 out)   (GEMM3: 128^2, 2 WGs/CU)
// R17 = R16 (best, 194.5us) + ONE surgical gemm1f change: Bn0's staging
// slack. R13-form issued Bn0(t+1) at P1 of tile t and retired it at the
// SAME tile's boundary (3 phases) because P4's bg0 reload kept the n0 LDS
// region busy. Now bg0 is held live across the tile (no P4 reload, +16
// VGPR) freeing n0 after P1, and Bn0(t+2) is staged at P2 -> 7 phases of
// slack, retired a tile later. A-path/Bn1/prologue-A identical to R13.
// vmcnt re-derived in-order: prologue 12; P2 auto-wait 8 (pa1 issued
// before Bn0); boundary 12/8/0.
// ---------------------------------------------------------------------------

typedef __bf16 bf16_t;
typedef __bf16 bf16x8 __attribute__((ext_vector_type(8)));
typedef __bf16 bf16x4 __attribute__((ext_vector_type(4)));
typedef float  f32x4  __attribute__((ext_vector_type(4)));

#define DEVI __device__ __forceinline__
#define BAR __builtin_amdgcn_s_barrier()
#define CFENCE asm volatile("" ::: "memory")

static constexpr int Mtok = 16384;   // tokens per batch
static constexpr int ROWS = 32768;   // B * Mtok

DEVI void gload_lds16(const void* g, void* l) {
  __builtin_amdgcn_global_load_lds(
      (__attribute__((address_space(1))) uint32_t*)(uintptr_t)g,
      (__attribute__((address_space(3))) uint32_t*)(uint32_t)(uintptr_t)l,
      16, 0, 0);
}

// chunked bijective XCD swizzle (identity when nwg % 8 != 0)
DEVI void xcd_swizzle(int gx, int* bx, int* by) {
  int nwg = gx * gridDim.y;
  if (nwg & 7) { *bx = blockIdx.x; *by = blockIdx.y; return; }
  int wg = blockIdx.x + gx * blockIdx.y;
  int swz = (wg & 7) * (nwg >> 3) + (wg >> 3);
  *bx = swz % gx;
  *by = swz / gx;
}

// ---------------- Hilbert permutation (n = 128 grid) -----------------------
__global__ void k_perm(int* __restrict__ perm) {
  int d = blockIdx.x * 256 + threadIdx.x;
  if (d >= Mtok) return;
  int t = d, x = 0, y = 0;
  for (int s = 1; s < 128; s <<= 1) {
    int rx = (t >> 1) & 1;
    int ry = (t ^ rx) & 1;
    if (ry == 0) {
      if (rx == 1) { x = s - 1 - x; y = s - 1 - y; }
      int tmp = x; x = y; y = tmp;
    }
    x += s * rx;
    y += s * ry;
    t >>= 2;
  }
  perm[d] = y * 128 + x;
}

// ---------------- weight prep: LDS-tiled transposes, one launch ------------
__global__ void k_prep_w(const float* __restrict__ Wq, const float* __restrict__ Wk,
                         const float* __restrict__ Wv, const float* __restrict__ Wqkv,
                         const float* __restrict__ Wout,
                         bf16_t* __restrict__ W1t, bf16_t* __restrict__ Wqkvt,
                         bf16_t* __restrict__ Woutt) {
  const int tb = blockIdx.x;
  const float* src; bf16_t* dst; int sC; long dstride; float scale; int tx, ty;
  if (tb < 192) {
    int m = tb / 64, t = tb % 64;
    src = (m == 0) ? Wq : (m == 1 ? Wk : Wv);
    dst = W1t + m * 512; sC = 512; dstride = 1536; scale = 1.0f / 3.0f;
    tx = t & 7; ty = t >> 3;
  } else if (tb < 384) {
    int t = tb - 192;
    src = Wqkv; dst = Wqkvt; sC = 1536; dstride = 512; scale = 1.0f;
    tx = t % 24; ty = t / 24;
  } else {
    int t = tb - 384;
    src = Wout; dst = Woutt; sC = 512; dstride = 512; scale = 1.0f;
    tx = t & 7; ty = t >> 3;
  }
  __shared__ float ld[64][65];
  const int tid = threadIdx.x, lane = tid & 15, rr = tid >> 4;
  const long r0 = (long)ty * 64, c0 = (long)tx * 64;
#pragma unroll
  for (int p = 0; p < 4; p++) {
    int r = rr + p * 16;
    float4 vv = *(const float4*)(src + (r0 + r) * sC + c0 + lane * 4);
    ld[r][lane * 4 + 0] = vv.x; ld[r][lane * 4 + 1] = vv.y;
    ld[r][lane * 4 + 2] = vv.z; ld[r][lane * 4 + 3] = vv.w;
  }
  __syncthreads();
#pragma unroll
  for (int p = 0; p < 4; p++) {
    int cc = rr + p * 16;              // dst row = src col c0+cc
    bf16x4 o;
#pragma unroll
    for (int i = 0; i < 4; i++) o[i] = (bf16_t)(ld[lane * 4 + i][cc] * scale);
    *(bf16x4*)(dst + (c0 + cc) * dstride + r0 + lane * 4) = o;
  }
}

// ---------------- staging helpers (256^2 kernels) ---------------------------
DEVI void stageB(const bf16_t* Bb, int Kdim, int k0, bf16_t* dst, int qsel,
                 int tid, int cswz) {
  int r = tid >> 3;
  int rb0 = (r >> 5) * 64 + qsel * 32 + (r & 31);
  const bf16_t* g = Bb + (long)rb0 * Kdim + k0 + cswz * 8;
  gload_lds16(g, dst + rb0 * 64 + (tid & 7) * 8);
  gload_lds16(g + (long)128 * Kdim, dst + (rb0 + 128) * 64 + (tid & 7) * 8);
}

// ---------------- fragment load / MFMA helpers (256^2, 8 waves) ------------
#define LOAD_AF(AF, QM, BUF)                                                   \
  _Pragma("unroll") for (int m = 0; m < 4; m++) {                              \
    int row = wm * 128 + (QM) * 64 + m * 16 + l15;                             \
    AF[m][0] = *(const bf16x8*)((BUF) + row * 64 + cb0 * 8);                   \
    AF[m][1] = *(const bf16x8*)((BUF) + row * 64 + cb1 * 8);                   \
  }
#define LOAD_BG(BG, QN, BUF)                                                   \
  _Pragma("unroll") for (int n = 0; n < 2; n++) {                              \
    int row = wn * 64 + (QN) * 32 + n * 16 + l15;                              \
    BG[n][0] = *(const bf16x8*)((BUF) + row * 64 + cb0 * 8);                   \
    BG[n][1] = *(const bf16x8*)((BUF) + row * 64 + cb1 * 8);                   \
  }
#define QUAD(QM, QN, AF, BG)                                                   \
  do {                                                                         \
    __builtin_amdgcn_s_setprio(1);                                             \
    _Pragma("unroll") for (int kh = 0; kh < 2; kh++)                           \
    _Pragma("unroll") for (int m = 0; m < 4; m++)                              \
    _Pragma("unroll") for (int n = 0; n < 2; n++)                              \
      acc[(QM)*4+m][(QN)*2+n] = __builtin_amdgcn_mfma_f32_16x16x32_bf16(       \
          AF[m][kh], BG[n][kh], acc[(QM)*4+m][(QN)*2+n], 0, 0, 0);             \
    __builtin_amdgcn_s_setprio(0);                                             \
  } while (0)

// ---------------- GEMM1 fused: A = [q|k|v] f32, converted in-kernel --------
DEVI const float* selsrc(int tt, const float* q, const float* k, const float* v) {
  return tt < 8 ? q : (tt < 16 ? k : v);
}

DEVI void loadAh(const float* S, long grow, int colf, float4* pa) {
  const float* p0 = S + grow * 512 + colf;
  pa[0] = *(const float4*)(p0);
  pa[1] = *(const float4*)(p0 + 4);
  const float* p1 = p0 + 128 * 512;
  pa[2] = *(const float4*)(p1);
  pa[3] = *(const float4*)(p1 + 4);
}

DEVI void writeAh(bf16_t* dst, int rbase, int cbt, const float4* pa) {
  bf16x8 o0, o1;
  o0[0] = (bf16_t)pa[0].x; o0[1] = (bf16_t)pa[0].y; o0[2] = (bf16_t)pa[0].z; o0[3] = (bf16_t)pa[0].w;
  o0[4] = (bf16_t)pa[1].x; o0[5] = (bf16_t)pa[1].y; o0[6] = (bf16_t)pa[1].z; o0[7] = (bf16_t)pa[1].w;
  o1[0] = (bf16_t)pa[2].x; o1[1] = (bf16_t)pa[2].y; o1[2] = (bf16_t)pa[2].z; o1[3] = (bf16_t)pa[2].w;
  o1[4] = (bf16_t)pa[3].x; o1[5] = (bf16_t)pa[3].y; o1[6] = (bf16_t)pa[3].z; o1[7] = (bf16_t)pa[3].w;
  int sw = (cbt ^ (rbase & 7)) * 8;
  *(bf16x8*)(dst + rbase * 64 + sw) = o0;
  *(bf16x8*)(dst + (rbase + 128) * 64 + sw) = o1;
}

__global__ __launch_bounds__(512, 2) void k_gemm1f(const float* __restrict__ q,
                                                   const float* __restrict__ k,
                                                   const float* __restrict__ v,
                                                   const bf16_t* __restrict__ Bt,
                                                   bf16_t* __restrict__ Cb,
                                                   int Ndim) {
  constexpr int Kdim = 1536;
  constexpr int NT = 24;
  __shared__ bf16_t lds[4 * 16384];  // 128 KiB
  const int tid = threadIdx.x;
  const int lane = tid & 63, w = tid >> 6;
  const int wm = w >> 2, wn = w & 3;
  const int l15 = lane & 15, l4 = lane >> 4;
  const int cb0 = l4 ^ (l15 & 7), cb1 = cb0 ^ 4;
  const int cswz = (tid & 7) ^ ((tid >> 3) & 7);
  const int cbt = tid & 7, rA = tid >> 3;
  int bx, by;
  xcd_swizzle(gridDim.x, &bx, &by);
  const long arow0 = (long)by * 256;
  const long bcol0 = (long)bx * 256;
  const bf16_t* Bb = Bt + bcol0 * Kdim;

  bf16_t* Acur = lds;
  bf16_t* Bcur = lds + 16384;
  bf16_t* Anxt = lds + 32768;
  bf16_t* Bnxt = lds + 49152;

  f32x4 acc[8][4] = {};
  float4 pa0[4], pa1[4];

  // ---- prologue ----
  loadAh(selsrc(0, q, k, v), arow0 + rA,      (cbt << 3), pa0);
  loadAh(selsrc(0, q, k, v), arow0 + rA + 64, (cbt << 3), pa1);
  writeAh(Acur, rA,      cbt, pa0);
  writeAh(Acur, rA + 64, cbt, pa1);
  stageB(Bb, Kdim, 0, Bcur, 0, tid, cswz);   // Bn0(0)
  stageB(Bb, Kdim, 0, Bcur, 1, tid, cswz);   // Bn1(0)
  loadAh(selsrc(1, q, k, v), arow0 + rA, 64 + (cbt << 3), pa0);  // Aq0(1)
  writeAh(Anxt, rA, cbt, pa0);                                    // -> nxt (auto-drain)
  stageB(Bb, Kdim, 64, Bnxt, 0, tid, cswz);  // Bn0(1) -> nxt
  stageB(Bb, Kdim, 64, Bnxt, 1, tid, cswz);  // Bn1(1) -> nxt
  loadAh(selsrc(1, q, k, v), arow0 + rA + 64,  64 + (cbt << 3), pa1);  // Aq1(1)
  loadAh(selsrc(2, q, k, v), arow0 + rA,      128 + (cbt << 3), pa0);  // Aq0(2)
  // outstanding: Bn0(1)2 + Bn1(1)2 + pa1 4 + pa0 4 = 12 (tile0 drained by
  // the compiler's auto-wait before writeAh(Anxt)).
  asm volatile("s_waitcnt vmcnt(12)" ::: "memory");
  asm volatile("s_waitcnt lgkmcnt(0)" ::: "memory");
  BAR;

  for (int t = 0; t < NT; t++) {
    bf16x8 af[4][2], bg0[2][2], bg1[2][2];
    // P1 (q0,n0): no staging; bg0 held live through P4 (frees n0-of-cur now)
    LOAD_AF(af, 0, Acur);
    LOAD_BG(bg0, 0, Bcur);
    QUAD(0, 0, af, bg0);
    BAR;
    // P2 (q0,n1): write Aq1(t+1)->nxt; load pa1 <- Aq1(t+2);
    //             stage Bn0(t+2)->cur (n0-of-cur free since P1; 7-phase slack)
    LOAD_BG(bg1, 1, Bcur);
    if (t + 1 < NT) writeAh(Anxt, rA + 64, cbt, pa1);
    if (t + 2 < NT) loadAh(selsrc(t + 2, q, k, v), arow0 + rA + 64,
                           (((t + 2) & 7) << 6) + (cbt << 3), pa1);
    if (t + 2 < NT) stageB(Bb, Kdim, (t + 2) * 64, Bcur, 0, tid, cswz);
    QUAD(0, 1, af, bg1);
    BAR;
    // P3 (q1,n1): write Aq0(t+2)->cur, load pa0 <- Aq0(t+3)
    LOAD_AF(af, 1, Acur);
    if (t + 2 < NT) writeAh(Acur, rA, cbt, pa0);
    if (t + 3 < NT) loadAh(selsrc(t + 3, q, k, v), arow0 + rA,
                           (((t + 3) & 7) << 6) + (cbt << 3), pa0);
    QUAD(1, 1, af, bg1);
    BAR;
    // P4 (q1,n0): stage Bn1(t+2)->cur; QUAD uses held bg0
    if (t + 2 < NT) stageB(Bb, Kdim, (t + 2) * 64, Bcur, 1, tid, cswz);
    QUAD(1, 0, af, bg0);
    // boundary: keep exactly this tile's issues =
    // pa1(4)+Bn0(2) [P2] + pa0(4) [P3] + Bn1(2) [P4] = 12 (8 / 0 at tails);
    // retires tile-(t-1)'s Bn1(t+1) and older -> tile t+1 fully landed.
    if (t + 3 < NT)      { asm volatile("s_waitcnt vmcnt(12)" ::: "memory"); }
    else if (t + 2 < NT) { asm volatile("s_waitcnt vmcnt(8)"  ::: "memory"); }
    else                 { asm volatile("s_waitcnt vmcnt(0)"  ::: "memory"); }
    asm volatile("s_waitcnt lgkmcnt(0)" ::: "memory");
    BAR;
    bf16_t* tA = Acur; Acur = Anxt; Anxt = tA;
    bf16_t* tB = Bcur; Bcur = Bnxt; Bnxt = tB;
  }

  // epilogue: C-write (bf16)
#pragma unroll
  for (int i = 0; i < 8; i++) {
#pragma unroll
    for (int j = 0; j < 4; j++) {
      long row = arow0 + wm * 128 + i * 16 + l4 * 4;
      long col = bcol0 + wn * 64 + j * 16 + l15;
#pragma unroll
      for (int r = 0; r < 4; r++)
        Cb[(row + r) * Ndim + col] = (bf16_t)acc[i][j][r];
    }
  }
}

// ---------------- 128^2 GEMM (bf16 A), ring-2, counted vmcnt, 2 WGs/CU -----
#define FRAGS_128                                                              \
  bf16x8 af[4][2], bg[4][2];                                                   \
  _Pragma("unroll") for (int m = 0; m < 4; m++) {                              \
    int row = wm * 64 + m * 16 + l15;                                          \
    af[m][0] = *(const bf16x8*)(Al + row * 64 + cb0 * 8);                      \
    af[m][1] = *(const bf16x8*)(Al + row * 64 + cb1 * 8);                      \
  }                                                                            \
  _Pragma("unroll") for (int n = 0; n < 4; n++) {                              \
    int row = wn * 64 + n * 16 + l15;                                          \
    bg[n][0] = *(const bf16x8*)(Bl + row * 64 + cb0 * 8);                      \
    bg[n][1] = *(const bf16x8*)(Bl + row * 64 + cb1 * 8);                      \
  }

#define MFMA_128                                                               \
  __builtin_amdgcn_s_setprio(1);                                               \
  _Pragma("unroll") for (int kh = 0; kh < 2; kh++)                             \
  _Pragma("unroll") for (int m = 0; m < 4; m++)                                \
  _Pragma("unroll") for (int n = 0; n < 4; n++)                                \
    acc[m][n] = __builtin_amdgcn_mfma_f32_16x16x32_bf16(af[m][kh], bg[n][kh],  \
                                                        acc[m][n], 0, 0, 0);   \
  __builtin_amdgcn_s_setprio(0);

template <bool OUTF32, int KD>
__global__ __launch_bounds__(256, 2) void k_gemm128(const bf16_t* __restrict__ A,
                                                    const bf16_t* __restrict__ Bt,
                                                    bf16_t* __restrict__ Cb,
                                                    float* __restrict__ Cf,
                                                    int Ndim) {
  constexpr int NT = KD / 64;
  __shared__ bf16_t lds[4][8192];   // 64 KiB: buf0{A,B}, buf1{A,B}
  const int tid = threadIdx.x, lane = tid & 63, w = tid >> 6;
  const int wm = w >> 1, wn = w & 1;
  const int l15 = lane & 15, l4 = lane >> 4;
  const int cb0 = l4 ^ (l15 & 7), cb1 = cb0 ^ 4;
  int bx, by;
  xcd_swizzle(gridDim.x, &bx, &by);
  const long arow0 = (long)by * 128;
  const long bcol0 = (long)bx * 128;

  auto stage = [&](int t, int buf) {
#pragma unroll
    for (int j = 0; j < 4; j++) {
      int cc = tid + j * 256;            // 1024 chunks of 8 bf16
      int row = cc >> 3;
      int sw = ((cc & 7) ^ (row & 7)) * 8;
      gload_lds16(A + (arow0 + row) * KD + t * 64 + sw, &lds[buf * 2][cc * 8]);
      gload_lds16(Bt + (bcol0 + row) * KD + t * 64 + sw, &lds[buf * 2 + 1][cc * 8]);
    }
  };

  f32x4 acc[4][4] = {};

  stage(0, 0);
  CFENCE;                                            // keep tile0 strictly older
  stage(1, 1);
  CFENCE;
  asm volatile("s_waitcnt vmcnt(8)" ::: "memory");   // tile0 landed
  BAR;
  CFENCE;

  for (int t = 0; t < NT - 2; t++) {
    const bf16_t* Al = lds[(t & 1) * 2];
    const bf16_t* Bl = lds[(t & 1) * 2 + 1];
    FRAGS_128;
    asm volatile("s_waitcnt lgkmcnt(0)" ::: "memory");
    BAR;
    CFENCE;
    stage(t + 2, t & 1);
    CFENCE;
    MFMA_128;
    asm volatile("s_waitcnt vmcnt(8)" ::: "memory"); // retire tile t+1
    BAR;
    CFENCE;
  }
  // t = NT-2 (no stage; retire last tile)
  {
    const bf16_t* Al = lds[(NT & 1) * 2];            // (NT-2)&1 == NT&1
    const bf16_t* Bl = lds[(NT & 1) * 2 + 1];
    FRAGS_128;
    asm volatile("s_waitcnt lgkmcnt(0)" ::: "memory");
    BAR;
    MFMA_128;
    asm volatile("s_waitcnt vmcnt(0)" ::: "memory");
    BAR;
    CFENCE;
  }
  // t = NT-1
  {
    const bf16_t* Al = lds[((NT - 1) & 1) * 2];
    const bf16_t* Bl = lds[((NT - 1) & 1) * 2 + 1];
    FRAGS_128;
    MFMA_128;
  }

#pragma unroll
  for (int m = 0; m < 4; m++) {
#pragma unroll
    for (int n = 0; n < 4; n++) {
      long row = arow0 + wm * 64 + m * 16 + l4 * 4;
      long col = bcol0 + wn * 64 + n * 16 + l15;
#pragma unroll
      for (int r = 0; r < 4; r++) {
        if constexpr (OUTF32) Cf[(row + r) * Ndim + col] = acc[m][n][r];
        else                  Cb[(row + r) * Ndim + col] = (bf16_t)acc[m][n][r];
      }
    }
  }
}

// ---------------- attention: one WG per (b, seg, head) ---------------------
__global__ __launch_bounds__(256, 2) void k_attn(const bf16_t* __restrict__ QKV,
                                                 const int* __restrict__ perm,
                                                 bf16_t* __restrict__ ATT) {
  __shared__ bf16_t Vt[2][64 * 64];
  __shared__ bf16_t P[2][64 * 64];
  __shared__ bf16_t O[128 * 64];
  __shared__ int perml[128];
  const int n = blockIdx.x, h = blockIdx.y, b = blockIdx.z;
  const int t = threadIdx.x;
  const int lane = t & 63, w = t >> 6;
  const int l15 = lane & 15, l4 = lane >> 4;

  if (t < 128) perml[t] = perm[n * 128 + t];
  __syncthreads();

#pragma unroll
  for (int it = 0; it < 4; it++) {
    int c = t + it * 256;
    int tok = c >> 3, c8 = c & 7;
    long j = (long)b * Mtok + perml[tok];
    bf16x8 vv = *(const bf16x8*)(QKV + j * 1536 + 1024 + h * 64 + c8 * 8);
    int grp = tok & 1, s = tok >> 1;
    bf16_t* vt = Vt[grp];
#pragma unroll
    for (int i = 0; i < 8; i++) {
      int d = c8 * 8 + i;
      vt[d * 64 + (s ^ ((d & 7) << 3))] = vv[i];
    }
  }

  const int grp = w >> 1, th = w & 1;

  f32x4 sc[2][4] = {};
#pragma unroll
  for (int ks = 0; ks < 2; ks++) {
    bf16x8 aq[2], bk[4];
#pragma unroll
    for (int tf = 0; tf < 2; tf++) {
      int tq = th * 32 + tf * 16 + l15;
      long j = (long)b * Mtok + perml[tq * 2 + grp];
      aq[tf] = *(const bf16x8*)(QKV + j * 1536 + h * 64 + ks * 32 + l4 * 8);
    }
#pragma unroll
    for (int sf = 0; sf < 4; sf++) {
      int s = sf * 16 + l15;
      long j = (long)b * Mtok + perml[s * 2 + grp];
      bk[sf] = *(const bf16x8*)(QKV + j * 1536 + 512 + h * 64 + ks * 32 + l4 * 8);
    }
#pragma unroll
    for (int tf = 0; tf < 2; tf++)
#pragma unroll
      for (int sf = 0; sf < 4; sf++)
        sc[tf][sf] = __builtin_amdgcn_mfma_f32_16x16x32_bf16(aq[tf], bk[sf], sc[tf][sf], 0, 0, 0);
  }

  const float scale = 0.125f;
#pragma unroll
  for (int tf = 0; tf < 2; tf++) {
#pragma unroll
    for (int r = 0; r < 4; r++) {
      float mx = fmaxf(fmaxf(sc[tf][0][r], sc[tf][1][r]), fmaxf(sc[tf][2][r], sc[tf][3][r]));
      mx = fmaxf(mx, __shfl_xor(mx, 1, 64));
      mx = fmaxf(mx, __shfl_xor(mx, 2, 64));
      mx = fmaxf(mx, __shfl_xor(mx, 4, 64));
      mx = fmaxf(mx, __shfl_xor(mx, 8, 64));
      float p0 = __expf((sc[tf][0][r] - mx) * scale);
      float p1 = __expf((sc[tf][1][r] - mx) * scale);
      float p2 = __expf((sc[tf][2][r] - mx) * scale);
      float p3 = __expf((sc[tf][3][r] - mx) * scale);
      float sum = p0 + p1 + p2 + p3;
      sum += __shfl_xor(sum, 1, 64);
      sum += __shfl_xor(sum, 2, 64);
      sum += __shfl_xor(sum, 4, 64);
      sum += __shfl_xor(sum, 8, 64);
      float inv = 1.0f / sum;
      int trow = th * 32 + tf * 16 + l4 * 4 + r;
      int sw = (trow & 7) << 3;
      bf16_t* pp = P[grp];
      pp[trow * 64 + ((l15     ) ^ sw)] = (bf16_t)(p0 * inv);
      pp[trow * 64 + ((l15 + 16) ^ sw)] = (bf16_t)(p1 * inv);
      pp[trow * 64 + ((l15 + 32) ^ sw)] = (bf16_t)(p2 * inv);
      pp[trow * 64 + ((l15 + 48) ^ sw)] = (bf16_t)(p3 * inv);
    }
  }
  __syncthreads();

  f32x4 oacc[2][4] = {};
#pragma unroll
  for (int ks = 0; ks < 2; ks++) {
    bf16x8 ap[2], bv[4];
#pragma unroll
    for (int tf = 0; tf < 2; tf++) {
      int trow = th * 32 + tf * 16 + l15;
      int cb = (ks * 4 + l4) ^ (trow & 7);
      ap[tf] = *(const bf16x8*)(P[grp] + trow * 64 + cb * 8);
    }
#pragma unroll
    for (int df = 0; df < 4; df++) {
      int d = df * 16 + l15;
      int cb = (ks * 4 + l4) ^ (d & 7);
      bv[df] = *(const bf16x8*)(Vt[grp] + d * 64 + cb * 8);
    }
#pragma unroll
    for (int tf = 0; tf < 2; tf++)
#pragma unroll
      for (int df = 0; df < 4; df++)
        oacc[tf][df] = __builtin_amdgcn_mfma_f32_16x16x32_bf16(ap[tf], bv[df], oacc[tf][df], 0, 0, 0);
  }

#pragma unroll
  for (int tf = 0; tf < 2; tf++)
#pragma unroll
    for (int df = 0; df < 4; df++)
#pragma unroll
      for (int r = 0; r < 4; r++) {
        int trow = th * 32 + tf * 16 + l4 * 4 + r;
        int tok = trow * 2 + grp;
        O[tok * 64 + df * 16 + l15] = (bf16_t)oacc[tf][df][r];
      }
  __syncthreads();
#pragma unroll
  for (int it = 0; it < 4; it++) {
    int c = t + it * 256;
    int tok = c >> 3, c8 = c & 7;
    long j = (long)b * Mtok + perml[tok];
    *(bf16x8*)(ATT + j * 512 + h * 64 + c8 * 8) = *(const bf16x8*)(O + tok * 64 + c8 * 8);
  }
}

// ---------------------------------------------------------------------------
extern "C" void kernel_launch(void* const* d_in, const int* in_sizes, int n_in,
                              void* d_out, int out_size, void* d_ws, size_t ws_size,
                              hipStream_t stream) {
  const float* q    = (const float*)d_in[0];
  const float* k    = (const float*)d_in[1];
  const float* v    = (const float*)d_in[2];
  const float* Wq   = (const float*)d_in[3];
  const float* Wk   = (const float*)d_in[4];
  const float* Wv   = (const float*)d_in[5];
  const float* Wqkv = (const float*)d_in[6];
  const float* Wout = (const float*)d_in[7];

  char* ws = (char*)d_ws;
  const size_t QKV_BYTES = (size_t)ROWS * 1536 * 2;  // 100,663,296
  const size_t X_BYTES   = (size_t)ROWS * 512 * 2;   //  33,554,432
  bf16_t* QKV   = (bf16_t*)ws;
  bf16_t* X     = (bf16_t*)(ws + QKV_BYTES);          // also ATT (X dead after GEMM2)
  bf16_t* W1t   = (bf16_t*)(ws + QKV_BYTES + X_BYTES);
  bf16_t* Wqkvt = W1t + 512 * 1536;
  bf16_t* Woutt = Wqkvt + 1536 * 512;
  int*    perm  = (int*)(Woutt + 512 * 512);

  k_perm<<<64, 256, 0, stream>>>(perm);
  k_prep_w<<<448, 256, 0, stream>>>(Wq, Wk, Wv, Wqkv, Wout, W1t, Wqkvt, Woutt);
  // GEMM1 (fused f32->bf16): X = [q|k|v] @ W1 (M=32768, N=512, K=1536)
  k_gemm1f<<<dim3(2, 128), 512, 0, stream>>>(q, k, v, W1t, X, 512);
  // GEMM2: QKV = X @ Wqkv (N=1536, K=512) - 128^2, 2 WGs/CU
  k_gemm128<false, 512><<<dim3(12, 256), 256, 0, stream>>>(X, Wqkvt, QKV, nullptr, 1536);
  // attention: reads QKV, writes ATT (aliases X)
  k_attn<<<dim3(128, 8, 2), 256, 0, stream>>>(QKV, perm, X);
  // GEMM3: out = ATT @ Wout (f32 output) - 128^2, 2 WGs/CU
  k_gemm128<true, 512><<<dim3(4, 256), 256, 0, stream>>>(X, Woutt, nullptr, (float*)d_out, 512);
}

// Round 18
// 190.371 us; speedup vs baseline: 1.1610x; 1.1610x over previous
//
#include <hip/hip_runtime.h>
#include <hip/hip_bf16.h>
#include <stdint.h>

// ---------------------------------------------------------------------------
// HilbertAttention pipeline, bf16 MFMA implementation.
//   x   = ([q|k|v] @ W1t^T)/3        (GEMM1 fused f32->bf16 A-staging, 256^2)
//   qkv = x @ Wqkvt^T                (GEMM2: 128^2, 2 WGs/CU)
//   attention (Hilbert perm computed inline, 128-seg, dil 2)
//   out = att @ Woutt^T  (f32 out)   (GEMM3: 128^2, 2 WGs/CU)
// R18 = R16 (best, 194.5us) with k_perm folded into k_attn (the 7-step
// Hilbert d2xy loop is cheaper inline than a kernel launch + global
// round-trip). gemm1f stays in its R13/R16 form: 10 variants (R14 128^2,
// R15 1024-thr spill, R17 bg0-hold spill, etc.) all regressed or nulled -
// 86us is this structure's register/latency knee.
// ---------------------------------------------------------------------------

typedef __bf16 bf16_t;
typedef __bf16 bf16x8 __attribute__((ext_vector_type(8)));
typedef __bf16 bf16x4 __attribute__((ext_vector_type(4)));
typedef float  f32x4  __attribute__((ext_vector_type(4)));

#define DEVI __device__ __forceinline__
#define BAR __builtin_amdgcn_s_barrier()
#define CFENCE asm volatile("" ::: "memory")

static constexpr int Mtok = 16384;   // tokens per batch
static constexpr int ROWS = 32768;   // B * Mtok

DEVI void gload_lds16(const void* g, void* l) {
  __builtin_amdgcn_global_load_lds(
      (__attribute__((address_space(1))) uint32_t*)(uintptr_t)g,
      (__attribute__((address_space(3))) uint32_t*)(uint32_t)(uintptr_t)l,
      16, 0, 0);
}

// chunked bijective XCD swizzle (identity when nwg % 8 != 0)
DEVI void xcd_swizzle(int gx, int* bx, int* by) {
  int nwg = gx * gridDim.y;
  if (nwg & 7) { *bx = blockIdx.x; *by = blockIdx.y; return; }
  int wg = blockIdx.x + gx * blockIdx.y;
  int swz = (wg & 7) * (nwg >> 3) + (wg >> 3);
  *bx = swz % gx;
  *by = swz / gx;
}

// Hilbert d2xy for a 128x128 grid: token index d -> row-major index.
DEVI int hilbert_d2i(int d) {
  int t = d, x = 0, y = 0;
  for (int s = 1; s < 128; s <<= 1) {
    int rx = (t >> 1) & 1;
    int ry = (t ^ rx) & 1;
    if (ry == 0) {
      if (rx == 1) { x = s - 1 - x; y = s - 1 - y; }
      int tmp = x; x = y; y = tmp;
    }
    x += s * rx;
    y += s * ry;
    t >>= 2;
  }
  return y * 128 + x;
}

// ---------------- weight prep: LDS-tiled transposes, one launch ------------
__global__ void k_prep_w(const float* __restrict__ Wq, const float* __restrict__ Wk,
                         const float* __restrict__ Wv, const float* __restrict__ Wqkv,
                         const float* __restrict__ Wout,
                         bf16_t* __restrict__ W1t, bf16_t* __restrict__ Wqkvt,
                         bf16_t* __restrict__ Woutt) {
  const int tb = blockIdx.x;
  const float* src; bf16_t* dst; int sC; long dstride; float scale; int tx, ty;
  if (tb < 192) {
    int m = tb / 64, t = tb % 64;
    src = (m == 0) ? Wq : (m == 1 ? Wk : Wv);
    dst = W1t + m * 512; sC = 512; dstride = 1536; scale = 1.0f / 3.0f;
    tx = t & 7; ty = t >> 3;
  } else if (tb < 384) {
    int t = tb - 192;
    src = Wqkv; dst = Wqkvt; sC = 1536; dstride = 512; scale = 1.0f;
    tx = t % 24; ty = t / 24;
  } else {
    int t = tb - 384;
    src = Wout; dst = Woutt; sC = 512; dstride = 512; scale = 1.0f;
    tx = t & 7; ty = t >> 3;
  }
  __shared__ float ld[64][65];
  const int tid = threadIdx.x, lane = tid & 15, rr = tid >> 4;
  const long r0 = (long)ty * 64, c0 = (long)tx * 64;
#pragma unroll
  for (int p = 0; p < 4; p++) {
    int r = rr + p * 16;
    float4 vv = *(const float4*)(src + (r0 + r) * sC + c0 + lane * 4);
    ld[r][lane * 4 + 0] = vv.x; ld[r][lane * 4 + 1] = vv.y;
    ld[r][lane * 4 + 2] = vv.z; ld[r][lane * 4 + 3] = vv.w;
  }
  __syncthreads();
#pragma unroll
  for (int p = 0; p < 4; p++) {
    int cc = rr + p * 16;              // dst row = src col c0+cc
    bf16x4 o;
#pragma unroll
    for (int i = 0; i < 4; i++) o[i] = (bf16_t)(ld[lane * 4 + i][cc] * scale);
    *(bf16x4*)(dst + (c0 + cc) * dstride + r0 + lane * 4) = o;
  }
}

// ---------------- staging helpers (256^2 kernels) ---------------------------
DEVI void stageB(const bf16_t* Bb, int Kdim, int k0, bf16_t* dst, int qsel,
                 int tid, int cswz) {
  int r = tid >> 3;
  int rb0 = (r >> 5) * 64 + qsel * 32 + (r & 31);
  const bf16_t* g = Bb + (long)rb0 * Kdim + k0 + cswz * 8;
  gload_lds16(g, dst + rb0 * 64 + (tid & 7) * 8);
  gload_lds16(g + (long)128 * Kdim, dst + (rb0 + 128) * 64 + (tid & 7) * 8);
}

// ---------------- fragment load / MFMA helpers (256^2, 8 waves) ------------
#define LOAD_AF(AF, QM, BUF)                                                   \
  _Pragma("unroll") for (int m = 0; m < 4; m++) {                              \
    int row = wm * 128 + (QM) * 64 + m * 16 + l15;                             \
    AF[m][0] = *(const bf16x8*)((BUF) + row * 64 + cb0 * 8);                   \
    AF[m][1] = *(const bf16x8*)((BUF) + row * 64 + cb1 * 8);                   \
  }
#define LOAD_BG(BG, QN, BUF)                                                   \
  _Pragma("unroll") for (int n = 0; n < 2; n++) {                              \
    int row = wn * 64 + (QN) * 32 + n * 16 + l15;                              \
    BG[n][0] = *(const bf16x8*)((BUF) + row * 64 + cb0 * 8);                   \
    BG[n][1] = *(const bf16x8*)((BUF) + row * 64 + cb1 * 8);                   \
  }
#define QUAD(QM, QN, AF, BG)                                                   \
  do {                                                                         \
    __builtin_amdgcn_s_setprio(1);                                             \
    _Pragma("unroll") for (int kh = 0; kh < 2; kh++)                           \
    _Pragma("unroll") for (int m = 0; m < 4; m++)                              \
    _Pragma("unroll") for (int n = 0; n < 2; n++)                              \
      acc[(QM)*4+m][(QN)*2+n] = __builtin_amdgcn_mfma_f32_16x16x32_bf16(       \
          AF[m][kh], BG[n][kh], acc[(QM)*4+m][(QN)*2+n], 0, 0, 0);             \
    __builtin_amdgcn_s_setprio(0);                                             \
  } while (0)

// ---------------- GEMM1 fused: A = [q|k|v] f32, converted in-kernel --------
DEVI const float* selsrc(int tt, const float* q, const float* k, const float* v) {
  return tt < 8 ? q : (tt < 16 ? k : v);
}

DEVI void loadAh(const float* S, long grow, int colf, float4* pa) {
  const float* p0 = S + grow * 512 + colf;
  pa[0] = *(const float4*)(p0);
  pa[1] = *(const float4*)(p0 + 4);
  const float* p1 = p0 + 128 * 512;
  pa[2] = *(const float4*)(p1);
  pa[3] = *(const float4*)(p1 + 4);
}

DEVI void writeAh(bf16_t* dst, int rbase, int cbt, const float4* pa) {
  bf16x8 o0, o1;
  o0[0] = (bf16_t)pa[0].x; o0[1] = (bf16_t)pa[0].y; o0[2] = (bf16_t)pa[0].z; o0[3] = (bf16_t)pa[0].w;
  o0[4] = (bf16_t)pa[1].x; o0[5] = (bf16_t)pa[1].y; o0[6] = (bf16_t)pa[1].z; o0[7] = (bf16_t)pa[1].w;
  o1[0] = (bf16_t)pa[2].x; o1[1] = (bf16_t)pa[2].y; o1[2] = (bf16_t)pa[2].z; o1[3] = (bf16_t)pa[2].w;
  o1[4] = (bf16_t)pa[3].x; o1[5] = (bf16_t)pa[3].y; o1[6] = (bf16_t)pa[3].z; o1[7] = (bf16_t)pa[3].w;
  int sw = (cbt ^ (rbase & 7)) * 8;
  *(bf16x8*)(dst + rbase * 64 + sw) = o0;
  *(bf16x8*)(dst + (rbase + 128) * 64 + sw) = o1;
}

__global__ __launch_bounds__(512, 2) void k_gemm1f(const float* __restrict__ q,
                                                   const float* __restrict__ k,
                                                   const float* __restrict__ v,
                                                   const bf16_t* __restrict__ Bt,
                                                   bf16_t* __restrict__ Cb,
                                                   int Ndim) {
  constexpr int Kdim = 1536;
  constexpr int NT = 24;
  __shared__ bf16_t lds[4 * 16384];  // 128 KiB
  const int tid = threadIdx.x;
  const int lane = tid & 63, w = tid >> 6;
  const int wm = w >> 2, wn = w & 3;
  const int l15 = lane & 15, l4 = lane >> 4;
  const int cb0 = l4 ^ (l15 & 7), cb1 = cb0 ^ 4;
  const int cswz = (tid & 7) ^ ((tid >> 3) & 7);
  const int cbt = tid & 7, rA = tid >> 3;
  int bx, by;
  xcd_swizzle(gridDim.x, &bx, &by);
  const long arow0 = (long)by * 256;
  const long bcol0 = (long)bx * 256;
  const bf16_t* Bb = Bt + bcol0 * Kdim;

  bf16_t* Acur = lds;
  bf16_t* Bcur = lds + 16384;
  bf16_t* Anxt = lds + 32768;
  bf16_t* Bnxt = lds + 49152;

  f32x4 acc[8][4] = {};
  float4 pa0[4], pa1[4];

  // ---- prologue ----
  loadAh(selsrc(0, q, k, v), arow0 + rA,      (cbt << 3), pa0);
  loadAh(selsrc(0, q, k, v), arow0 + rA + 64, (cbt << 3), pa1);
  writeAh(Acur, rA,      cbt, pa0);
  writeAh(Acur, rA + 64, cbt, pa1);
  stageB(Bb, Kdim, 0, Bcur, 0, tid, cswz);   // Bn0(0)
  stageB(Bb, Kdim, 0, Bcur, 1, tid, cswz);   // Bn1(0)
  loadAh(selsrc(1, q, k, v), arow0 + rA, 64 + (cbt << 3), pa0);  // Aq0(1)
  writeAh(Anxt, rA, cbt, pa0);                                    // -> nxt
  stageB(Bb, Kdim, 64, Bnxt, 1, tid, cswz);  // Bn1(1) -> nxt
  loadAh(selsrc(1, q, k, v), arow0 + rA + 64,  64 + (cbt << 3), pa1);  // Aq1(1)
  loadAh(selsrc(2, q, k, v), arow0 + rA,      128 + (cbt << 3), pa0);  // Aq0(2)
  // outstanding here: Bn1(1)x2 + pa1 x4 + pa0 x4 = 10 (tile0 B already
  // retired by the compiler's wait before writeAh(Anxt)).
  asm volatile("s_waitcnt vmcnt(10)" ::: "memory");
  asm volatile("s_waitcnt lgkmcnt(0)" ::: "memory");
  BAR;

  for (int t = 0; t < NT; t++) {
    bf16x8 af[4][2], bg0[2][2], bg1[2][2];
    // P1 (q0,n0): stage Bn0(t+1)->nxt
    LOAD_AF(af, 0, Acur);
    LOAD_BG(bg0, 0, Bcur);
    if (t + 1 < NT) stageB(Bb, Kdim, (t + 1) * 64, Bnxt, 0, tid, cswz);
    QUAD(0, 0, af, bg0);
    BAR;
    // P2 (q0,n1): write Aq1(t+1)->nxt, then load pa1 <- Aq1(t+2)
    LOAD_BG(bg1, 1, Bcur);
    if (t + 1 < NT) writeAh(Anxt, rA + 64, cbt, pa1);
    if (t + 2 < NT) loadAh(selsrc(t + 2, q, k, v), arow0 + rA + 64,
                           (((t + 2) & 7) << 6) + (cbt << 3), pa1);
    QUAD(0, 1, af, bg1);
    BAR;
    // P3 (q1,n1): write Aq0(t+2)->cur, load pa0 <- Aq0(t+3)
    LOAD_AF(af, 1, Acur);
    if (t + 2 < NT) writeAh(Acur, rA, cbt, pa0);
    if (t + 3 < NT) loadAh(selsrc(t + 3, q, k, v), arow0 + rA,
                           (((t + 3) & 7) << 6) + (cbt << 3), pa0);
    QUAD(1, 1, af, bg1);
    BAR;
    // P4 (q1,n0): stage Bn1(t+2)->cur
    LOAD_BG(bg0, 0, Bcur);
    if (t + 2 < NT) stageB(Bb, Kdim, (t + 2) * 64, Bcur, 1, tid, cswz);
    QUAD(1, 0, af, bg0);
    // boundary: retire Bn0(t+1)@P1 and older; keep newest =
    // pa1(t+2)4 + pa0(t+3)4 + Bn1(t+2)2 = 10 (6 when pa0-load skipped).
    if (t + 3 < NT)      { asm volatile("s_waitcnt vmcnt(10)" ::: "memory"); }
    else if (t + 2 < NT) { asm volatile("s_waitcnt vmcnt(6)"  ::: "memory"); }
    else                 { asm volatile("s_waitcnt vmcnt(0)"  ::: "memory"); }
    asm volatile("s_waitcnt lgkmcnt(0)" ::: "memory");
    BAR;
    bf16_t* tA = Acur; Acur = Anxt; Anxt = tA;
    bf16_t* tB = Bcur; Bcur = Bnxt; Bnxt = tB;
  }

  // epilogue: C-write (bf16)
#pragma unroll
  for (int i = 0; i < 8; i++) {
#pragma unroll
    for (int j = 0; j < 4; j++) {
      long row = arow0 + wm * 128 + i * 16 + l4 * 4;
      long col = bcol0 + wn * 64 + j * 16 + l15;
#pragma unroll
      for (int r = 0; r < 4; r++)
        Cb[(row + r) * Ndim + col] = (bf16_t)acc[i][j][r];
    }
  }
}

// ---------------- 128^2 GEMM (bf16 A), ring-2, counted vmcnt, 2 WGs/CU -----
#define FRAGS_128                                                              \
  bf16x8 af[4][2], bg[4][2];                                                   \
  _Pragma("unroll") for (int m = 0; m < 4; m++) {                              \
    int row = wm * 64 + m * 16 + l15;                                          \
    af[m][0] = *(const bf16x8*)(Al + row * 64 + cb0 * 8);                      \
    af[m][1] = *(const bf16x8*)(Al + row * 64 + cb1 * 8);                      \
  }                                                                            \
  _Pragma("unroll") for (int n = 0; n < 4; n++) {                              \
    int row = wn * 64 + n * 16 + l15;                                          \
    bg[n][0] = *(const bf16x8*)(Bl + row * 64 + cb0 * 8);                      \
    bg[n][1] = *(const bf16x8*)(Bl + row * 64 + cb1 * 8);                      \
  }

#define MFMA_128                                                               \
  __builtin_amdgcn_s_setprio(1);                                               \
  _Pragma("unroll") for (int kh = 0; kh < 2; kh++)                             \
  _Pragma("unroll") for (int m = 0; m < 4; m++)                                \
  _Pragma("unroll") for (int n = 0; n < 4; n++)                                \
    acc[m][n] = __builtin_amdgcn_mfma_f32_16x16x32_bf16(af[m][kh], bg[n][kh],  \
                                                        acc[m][n], 0, 0, 0);   \
  __builtin_amdgcn_s_setprio(0);

template <bool OUTF32, int KD>
__global__ __launch_bounds__(256, 2) void k_gemm128(const bf16_t* __restrict__ A,
                                                    const bf16_t* __restrict__ Bt,
                                                    bf16_t* __restrict__ Cb,
                                                    float* __restrict__ Cf,
                                                    int Ndim) {
  constexpr int NT = KD / 64;
  __shared__ bf16_t lds[4][8192];   // 64 KiB: buf0{A,B}, buf1{A,B}
  const int tid = threadIdx.x, lane = tid & 63, w = tid >> 6;
  const int wm = w >> 1, wn = w & 1;
  const int l15 = lane & 15, l4 = lane >> 4;
  const int cb0 = l4 ^ (l15 & 7), cb1 = cb0 ^ 4;
  int bx, by;
  xcd_swizzle(gridDim.x, &bx, &by);
  const long arow0 = (long)by * 128;
  const long bcol0 = (long)bx * 128;

  auto stage = [&](int t, int buf) {
#pragma unroll
    for (int j = 0; j < 4; j++) {
      int cc = tid + j * 256;            // 1024 chunks of 8 bf16
      int row = cc >> 3;
      int sw = ((cc & 7) ^ (row & 7)) * 8;
      gload_lds16(A + (arow0 + row) * KD + t * 64 + sw, &lds[buf * 2][cc * 8]);
      gload_lds16(Bt + (bcol0 + row) * KD + t * 64 + sw, &lds[buf * 2 + 1][cc * 8]);
    }
  };

  f32x4 acc[4][4] = {};

  stage(0, 0);
  CFENCE;                                            // keep tile0 strictly older
  stage(1, 1);
  CFENCE;
  asm volatile("s_waitcnt vmcnt(8)" ::: "memory");   // tile0 landed
  BAR;
  CFENCE;

  for (int t = 0; t < NT - 2; t++) {
    const bf16_t* Al = lds[(t & 1) * 2];
    const bf16_t* Bl = lds[(t & 1) * 2 + 1];
    FRAGS_128;
    asm volatile("s_waitcnt lgkmcnt(0)" ::: "memory");
    BAR;
    CFENCE;
    stage(t + 2, t & 1);
    CFENCE;
    MFMA_128;
    asm volatile("s_waitcnt vmcnt(8)" ::: "memory"); // retire tile t+1
    BAR;
    CFENCE;
  }
  // t = NT-2 (no stage; retire last tile)
  {
    const bf16_t* Al = lds[(NT & 1) * 2];            // (NT-2)&1 == NT&1
    const bf16_t* Bl = lds[(NT & 1) * 2 + 1];
    FRAGS_128;
    asm volatile("s_waitcnt lgkmcnt(0)" ::: "memory");
    BAR;
    MFMA_128;
    asm volatile("s_waitcnt vmcnt(0)" ::: "memory");
    BAR;
    CFENCE;
  }
  // t = NT-1
  {
    const bf16_t* Al = lds[((NT - 1) & 1) * 2];
    const bf16_t* Bl = lds[((NT - 1) & 1) * 2 + 1];
    FRAGS_128;
    MFMA_128;
  }

#pragma unroll
  for (int m = 0; m < 4; m++) {
#pragma unroll
    for (int n = 0; n < 4; n++) {
      long row = arow0 + wm * 64 + m * 16 + l4 * 4;
      long col = bcol0 + wn * 64 + n * 16 + l15;
#pragma unroll
      for (int r = 0; r < 4; r++) {
        if constexpr (OUTF32) Cf[(row + r) * Ndim + col] = acc[m][n][r];
        else                  Cb[(row + r) * Ndim + col] = (bf16_t)acc[m][n][r];
      }
    }
  }
}

// ---------------- attention: one WG per (b, seg, head); inline Hilbert -----
__global__ __launch_bounds__(256, 2) void k_attn(const bf16_t* __restrict__ QKV,
                                                 bf16_t* __restrict__ ATT) {
  __shared__ bf16_t Vt[2][64 * 64];
  __shared__ bf16_t P[2][64 * 64];
  __shared__ bf16_t O[128 * 64];
  __shared__ int perml[128];
  const int n = blockIdx.x, h = blockIdx.y, b = blockIdx.z;
  const int t = threadIdx.x;
  const int lane = t & 63, w = t >> 6;
  const int l15 = lane & 15, l4 = lane >> 4;

  if (t < 128) perml[t] = hilbert_d2i(n * 128 + t);
  __syncthreads();

#pragma unroll
  for (int it = 0; it < 4; it++) {
    int c = t + it * 256;
    int tok = c >> 3, c8 = c & 7;
    long j = (long)b * Mtok + perml[tok];
    bf16x8 vv = *(const bf16x8*)(QKV + j * 1536 + 1024 + h * 64 + c8 * 8);
    int grp = tok & 1, s = tok >> 1;
    bf16_t* vt = Vt[grp];
#pragma unroll
    for (int i = 0; i < 8; i++) {
      int d = c8 * 8 + i;
      vt[d * 64 + (s ^ ((d & 7) << 3))] = vv[i];
    }
  }

  const int grp = w >> 1, th = w & 1;

  f32x4 sc[2][4] = {};
#pragma unroll
  for (int ks = 0; ks < 2; ks++) {
    bf16x8 aq[2], bk[4];
#pragma unroll
    for (int tf = 0; tf < 2; tf++) {
      int tq = th * 32 + tf * 16 + l15;
      long j = (long)b * Mtok + perml[tq * 2 + grp];
      aq[tf] = *(const bf16x8*)(QKV + j * 1536 + h * 64 + ks * 32 + l4 * 8);
    }
#pragma unroll
    for (int sf = 0; sf < 4; sf++) {
      int s = sf * 16 + l15;
      long j = (long)b * Mtok + perml[s * 2 + grp];
      bk[sf] = *(const bf16x8*)(QKV + j * 1536 + 512 + h * 64 + ks * 32 + l4 * 8);
    }
#pragma unroll
    for (int tf = 0; tf < 2; tf++)
#pragma unroll
      for (int sf = 0; sf < 4; sf++)
        sc[tf][sf] = __builtin_amdgcn_mfma_f32_16x16x32_bf16(aq[tf], bk[sf], sc[tf][sf], 0, 0, 0);
  }

  const float scale = 0.125f;
#pragma unroll
  for (int tf = 0; tf < 2; tf++) {
#pragma unroll
    for (int r = 0; r < 4; r++) {
      float mx = fmaxf(fmaxf(sc[tf][0][r], sc[tf][1][r]), fmaxf(sc[tf][2][r], sc[tf][3][r]));
      mx = fmaxf(mx, __shfl_xor(mx, 1, 64));
      mx = fmaxf(mx, __shfl_xor(mx, 2, 64));
      mx = fmaxf(mx, __shfl_xor(mx, 4, 64));
      mx = fmaxf(mx, __shfl_xor(mx, 8, 64));
      float p0 = __expf((sc[tf][0][r] - mx) * scale);
      float p1 = __expf((sc[tf][1][r] - mx) * scale);
      float p2 = __expf((sc[tf][2][r] - mx) * scale);
      float p3 = __expf((sc[tf][3][r] - mx) * scale);
      float sum = p0 + p1 + p2 + p3;
      sum += __shfl_xor(sum, 1, 64);
      sum += __shfl_xor(sum, 2, 64);
      sum += __shfl_xor(sum, 4, 64);
      sum += __shfl_xor(sum, 8, 64);
      float inv = 1.0f / sum;
      int trow = th * 32 + tf * 16 + l4 * 4 + r;
      int sw = (trow & 7) << 3;
      bf16_t* pp = P[grp];
      pp[trow * 64 + ((l15     ) ^ sw)] = (bf16_t)(p0 * inv);
      pp[trow * 64 + ((l15 + 16) ^ sw)] = (bf16_t)(p1 * inv);
      pp[trow * 64 + ((l15 + 32) ^ sw)] = (bf16_t)(p2 * inv);
      pp[trow * 64 + ((l15 + 48) ^ sw)] = (bf16_t)(p3 * inv);
    }
  }
  __syncthreads();

  f32x4 oacc[2][4] = {};
#pragma unroll
  for (int ks = 0; ks < 2; ks++) {
    bf16x8 ap[2], bv[4];
#pragma unroll
    for (int tf = 0; tf < 2; tf++) {
      int trow = th * 32 + tf * 16 + l15;
      int cb = (ks * 4 + l4) ^ (trow & 7);
      ap[tf] = *(const bf16x8*)(P[grp] + trow * 64 + cb * 8);
    }
#pragma unroll
    for (int df = 0; df < 4; df++) {
      int d = df * 16 + l15;
      int cb = (ks * 4 + l4) ^ (d & 7);
      bv[df] = *(const bf16x8*)(Vt[grp] + d * 64 + cb * 8);
    }
#pragma unroll
    for (int tf = 0; tf < 2; tf++)
#pragma unroll
      for (int df = 0; df < 4; df++)
        oacc[tf][df] = __builtin_amdgcn_mfma_f32_16x16x32_bf16(ap[tf], bv[df], oacc[tf][df], 0, 0, 0);
  }

#pragma unroll
  for (int tf = 0; tf < 2; tf++)
#pragma unroll
    for (int df = 0; df < 4; df++)
#pragma unroll
      for (int r = 0; r < 4; r++) {
        int trow = th * 32 + tf * 16 + l4 * 4 + r;
        int tok = trow * 2 + grp;
        O[tok * 64 + df * 16 + l15] = (bf16_t)oacc[tf][df][r];
      }
  __syncthreads();
#pragma unroll
  for (int it = 0; it < 4; it++) {
    int c = t + it * 256;
    int tok = c >> 3, c8 = c & 7;
    long j = (long)b * Mtok + perml[tok];
    *(bf16x8*)(ATT + j * 512 + h * 64 + c8 * 8) = *(const bf16x8*)(O + tok * 64 + c8 * 8);
  }
}

// ---------------------------------------------------------------------------
extern "C" void kernel_launch(void* const* d_in, const int* in_sizes, int n_in,
                              void* d_out, int out_size, void* d_ws, size_t ws_size,
                              hipStream_t stream) {
  const float* q    = (const float*)d_in[0];
  const float* k    = (const float*)d_in[1];
  const float* v    = (const float*)d_in[2];
  const float* Wq   = (const float*)d_in[3];
  const float* Wk   = (const float*)d_in[4];
  const float* Wv   = (const float*)d_in[5];
  const float* Wqkv = (const float*)d_in[6];
  const float* Wout = (const float*)d_in[7];

  char* ws = (char*)d_ws;
  const size_t QKV_BYTES = (size_t)ROWS * 1536 * 2;  // 100,663,296
  const size_t X_BYTES   = (size_t)ROWS * 512 * 2;   //  33,554,432
  bf16_t* QKV   = (bf16_t*)ws;
  bf16_t* X     = (bf16_t*)(ws + QKV_BYTES);          // also ATT (X dead after GEMM2)
  bf16_t* W1t   = (bf16_t*)(ws + QKV_BYTES + X_BYTES);
  bf16_t* Wqkvt = W1t + 512 * 1536;
  bf16_t* Woutt = Wqkvt + 1536 * 512;

  k_prep_w<<<448, 256, 0, stream>>>(Wq, Wk, Wv, Wqkv, Wout, W1t, Wqkvt, Woutt);
  // GEMM1 (fused f32->bf16): X = [q|k|v] @ W1 (M=32768, N=512, K=1536)
  k_gemm1f<<<dim3(2, 128), 512, 0, stream>>>(q, k, v, W1t, X, 512);
  // GEMM2: QKV = X @ Wqkv (N=1536, K=512) - 128^2, 2 WGs/CU
  k_gemm128<false, 512><<<dim3(12, 256), 256, 0, stream>>>(X, Wqkvt, QKV, nullptr, 1536);
  // attention (Hilbert perm inline): reads QKV, writes ATT (aliases X)
  k_attn<<<dim3(128, 8, 2), 256, 0, stream>>>(QKV, X);
  // GEMM3: out = ATT @ Wout (f32 output) - 128^2, 2 WGs/CU
  k_gemm128<true, 512><<<dim3(4, 256), 256, 0, stream>>>(X, Woutt, nullptr, (float*)d_out, 512);
}